// Round 10
// baseline (268.187 us; speedup 1.0000x reference)
//
#include <hip/hip_runtime.h>

// Problem constants
constexpr int B  = 16;
constexpr int LT = 512;
constexpr int D  = 1024;
constexpr int N  = 4096;
constexpr int H  = 16;
constexpr int DH = D / H;       // 64
constexpr int LMAX = N / B;     // 256
constexpr float LN_EPS = 1e-5f;

typedef short  s16x8 __attribute__((ext_vector_type(8)));
typedef float  f32x4 __attribute__((ext_vector_type(4)));

__device__ __forceinline__ unsigned short f2bf(float x) {
    unsigned int u = __float_as_uint(x);
    unsigned int r = (u + 0x7fffu + ((u >> 16) & 1u)) >> 16;   // RNE
    return (unsigned short)r;
}
__device__ __forceinline__ float bf2f(unsigned short u) {
    return __uint_as_float((unsigned int)u << 16);
}

__device__ __forceinline__ void load_lds16(const void* g, void* l) {
    __builtin_amdgcn_global_load_lds(
        (const __attribute__((address_space(1))) unsigned int*)g,
        (__attribute__((address_space(3))) unsigned int*)l, 16, 0, 0);
}

// ---------------------------------------------------------------------------
// Dispatch 1: casts + prep + scatter + msum-zero, all in one grid.
//   blocks [0,6144):       fp32->bf16 casts of text / wqkv / wattn
//   block  6144:           counts/starts (for lnmean)
//   blocks [6145,6273):    scatter: 128 blocks, each = (batch b, 32 slots);
//                          computes its own count/start from sb (no dep on 6144)
//   block  6273:           zero msum (16K floats)
__global__ __launch_bounds__(256) void cast3_prep_scatter(
        const float* __restrict__ x0, unsigned short* __restrict__ y0, int n0,
        const float* __restrict__ x1, unsigned short* __restrict__ y1, int n1,
        const float* __restrict__ x2, unsigned short* __restrict__ y2, int n2,
        const int* __restrict__ sb, int* __restrict__ counts, int* __restrict__ starts,
        const float* __restrict__ st, unsigned short* __restrict__ padded,
        float* __restrict__ msum) {
    int t = threadIdx.x;
    int bid = blockIdx.x;
    if (bid < 6144) {   // casts
        long long i = (long long)(bid * 256 + t) * 8;
        const float* x; unsigned short* y;
        if (i < n0)                { x = x0 + i; y = y0 + i; }
        else if (i < (long long)n0 + n1) { long long j = i - n0; x = x1 + j; y = y1 + j; }
        else if (i < (long long)n0 + n1 + n2) { long long j = i - n0 - n1; x = x2 + j; y = y2 + j; }
        else return;
        float4 a = *(const float4*)x;
        float4 b = *(const float4*)(x + 4);
        ushort4 o1, o2;
        o1.x = f2bf(a.x); o1.y = f2bf(a.y); o1.z = f2bf(a.z); o1.w = f2bf(a.w);
        o2.x = f2bf(b.x); o2.y = f2bf(b.y); o2.z = f2bf(b.z); o2.w = f2bf(b.w);
        *(ushort4*)y = o1;
        *(ushort4*)(y + 4) = o2;
        return;
    }
    if (bid == 6144) {  // prep (consumed by lnmean)
        __shared__ int s_counts[B];
        if (t < B) s_counts[t] = 0;
        __syncthreads();
        for (int i = t; i < N; i += 256) atomicAdd(&s_counts[sb[i]], 1);
        __syncthreads();
        if (t == 0) {
            int run = 0;
            for (int b = 0; b < B; b++) { starts[b] = run; run += s_counts[b]; }
        }
        if (t < B) counts[t] = s_counts[t];
        return;
    }
    if (bid == 6273) {  // zero msum
        float4 z = {0.f, 0.f, 0.f, 0.f};
#pragma unroll
        for (int j = 0; j < 4; j++)
            *(float4*)&msum[(t * 4 + j) * 4] = z;
        return;
    }
    // scatter: sidx in [0,128) -> batch b = sidx>>3, slots p0..p0+31
    int sidx = bid - 6145;
    int b = sidx >> 3;
    int p0 = (sidx & 7) * 32;
    // self-computed count/start for b
    __shared__ int red[8];
    int cl = 0, sl = 0;
    for (int i = t; i < N; i += 256) {
        int v = sb[i];
        cl += (v == b);
        sl += (v < b);
    }
#pragma unroll
    for (int o = 32; o; o >>= 1) { cl += __shfl_xor(cl, o); sl += __shfl_xor(sl, o); }
    int wv = t >> 6;
    if ((t & 63) == 0) { red[wv] = cl; red[4 + wv] = sl; }
    __syncthreads();
    int cnt = red[0] + red[1] + red[2] + red[3];
    int st0 = red[4] + red[5] + red[6] + red[7];
    int d = t * 4;
    for (int p = p0; p < p0 + 32; p++) {
        ushort4 o = {0, 0, 0, 0};
        if (p < cnt) {
            float4 v = *(const float4*)&st[(size_t)(st0 + p) * D + d];
            o.x = f2bf(v.x); o.y = f2bf(v.y); o.z = f2bf(v.z); o.w = f2bf(v.w);
        }
        *(ushort4*)&padded[((size_t)(b * LMAX + p)) * D + d] = o;
    }
}

// ---------------------------------------------------------------------------
// GEMM tile body, K range [kbeg,kend), row stride K. BK=64 (two 32-panels per
// barrier pair). epi(m, n, val) per element.
constexpr int PANEL = 128 * 32;

template<typename Epi>
__device__ __forceinline__ void gemm_tile_e(const unsigned short* __restrict__ A,
                                            const unsigned short* __restrict__ W,
                                            int K, int kbeg, int kend, int m0, int n0,
                                            unsigned short* As, unsigned short* Bs,
                                            Epi&& epi) {
    const int tid  = threadIdx.x;
    const int lane = tid & 63;
    const int wave = tid >> 6;
    const int wm = (wave >> 1) * 64, wn = (wave & 1) * 64;

    const int srow = tid >> 2;
    const int scol = (tid & 3) * 8;
    const unsigned short* Ag = A + (size_t)(m0 + srow) * K + scol;
    const unsigned short* Wg = W + (size_t)(n0 + srow) * K + scol;
    unsigned short* Asl = As + tid * 8;
    unsigned short* Bsl = Bs + tid * 8;

    const int fm = lane & 15;
    const int fk = (lane >> 4) * 8;

    f32x4 acc[4][4];
#pragma unroll
    for (int i = 0; i < 4; i++)
#pragma unroll
        for (int j = 0; j < 4; j++) acc[i][j] = (f32x4){0.f, 0.f, 0.f, 0.f};

    for (int k0 = kbeg; k0 < kend; k0 += 64) {
        __syncthreads();
        load_lds16(Ag + k0, Asl);
        load_lds16(Ag + (size_t)64 * K + k0, Asl + 64 * 32);
        load_lds16(Wg + k0, Bsl);
        load_lds16(Wg + (size_t)64 * K + k0, Bsl + 64 * 32);
        load_lds16(Ag + k0 + 32, Asl + PANEL);
        load_lds16(Ag + (size_t)64 * K + k0 + 32, Asl + PANEL + 64 * 32);
        load_lds16(Wg + k0 + 32, Bsl + PANEL);
        load_lds16(Wg + (size_t)64 * K + k0 + 32, Bsl + PANEL + 64 * 32);
        __syncthreads();

#pragma unroll
        for (int hp = 0; hp < 2; hp++) {
            const unsigned short* Ap = As + hp * PANEL;
            const unsigned short* Bp = Bs + hp * PANEL;
            s16x8 af[4], bf[4];
#pragma unroll
            for (int i = 0; i < 4; i++) {
                af[i] = *(const s16x8*)&Ap[(wm + i * 16 + fm) * 32 + fk];
                bf[i] = *(const s16x8*)&Bp[(wn + i * 16 + fm) * 32 + fk];
            }
#pragma unroll
            for (int i = 0; i < 4; i++)
#pragma unroll
                for (int j = 0; j < 4; j++)
                    acc[i][j] = __builtin_amdgcn_mfma_f32_16x16x32_bf16(af[i], bf[j], acc[i][j], 0, 0, 0);
        }
    }

    const int fr = (lane >> 4) * 4;
#pragma unroll
    for (int j = 0; j < 4; j++) {
        int col = n0 + wn + j * 16 + fm;
#pragma unroll
        for (int i = 0; i < 4; i++) {
            int row = m0 + wm + i * 16 + fr;
#pragma unroll
            for (int r = 0; r < 4; r++)
                epi(row + r, col, acc[i][j][r]);
        }
    }
}

// Fused QKV with XCD-aware block swizzle (A-tile sharers -> same XCD).
__global__ __launch_bounds__(256) void qkv_fused(const unsigned short* __restrict__ padded,
                                                 const unsigned short* __restrict__ text,
                                                 const unsigned short* __restrict__ wqkv,
                                                 const float* __restrict__ bqkv,
                                                 unsigned short* __restrict__ qpack,
                                                 unsigned short* __restrict__ kpack,
                                                 unsigned short* __restrict__ vpack) {
    __shared__ __align__(16) unsigned short As[2 * PANEL];
    __shared__ __align__(16) unsigned short Bs[2 * PANEL];
    int flat = blockIdx.x;
    if (flat < 256) {
        int m = flat & 31, n = flat >> 5;
        gemm_tile_e(padded, wqkv, D, 0, D, m * 128, n * 128, As, Bs,
            [&](int mm, int col, float v) {
                float val = v + bqkv[col];
                int b = mm >> 8, q = mm & 255;
                int h = col >> 6, d = col & 63;
                qpack[(size_t)(b * H + h) * 16384 + (d >> 3) * 2048 + q * 8 + (d & 7)] = f2bf(val);
            });
    } else if (flat < 768) {
        int f = flat - 256;
        int m = f & 63, n = f >> 6;
        gemm_tile_e(text, wqkv + (size_t)D * D, D, 0, D, m * 128, n * 128, As, Bs,
            [&](int mm, int col, float v) {
                float val = v + bqkv[D + col];
                int b = mm >> 9, key = mm & 511;
                int h = col >> 6, d = col & 63;
                kpack[(size_t)(b * H + h) * 32768 + (d >> 3) * 4096 + key * 8 + (d & 7)] = f2bf(val);
            });
    } else {
        int f = flat - 768;
        int m = f >> 6, n = f & 63;
        gemm_tile_e(wqkv + 2 * (size_t)D * D, text, D, 0, D, m * 128, n * 128, As, Bs,
            [&](int mm, int col, float v) {
                float val = v + bqkv[2 * D + mm];
                int h = mm >> 6, d = mm & 63;
                int b = col >> 9, key = col & 511;
                vpack[(size_t)(b * H + h) * 32768 + (key >> 3) * 512 + d * 8 + (key & 7)] = f2bf(val);
            });
    }
}

// attn_out GEMM, split-K=2, bf16 partial outputs (bias added in lnmean).
__global__ __launch_bounds__(256) void gemm_bf2(const unsigned short* __restrict__ A,
                                                const unsigned short* __restrict__ W,
                                                unsigned short* __restrict__ C0,
                                                unsigned short* __restrict__ C1,
                                                int Nn, int K) {
    __shared__ __align__(16) unsigned short As[2 * PANEL];
    __shared__ __align__(16) unsigned short Bs[2 * PANEL];
    int id = blockIdx.x;
    int kh = id >> 8;
    int n  = (id & 255) >> 5;
    int m  = id & 31;
    unsigned short* C = kh ? C1 : C0;
    gemm_tile_e(A, W, K, kh * 512, (kh + 1) * 512, m * 128, n * 128, As, Bs,
        [&](int mm, int col, float v) {
            C[(size_t)mm * Nn + col] = f2bf(v);
        });
}

// ---------------------------------------------------------------------------
// Flash MFMA attention: block = (b, h, q-half), 512 thr = 8 waves x 16 q-rows.
// Online softmax over 4 chunks of 128 keys; K+V chunks staged together per
// barrier pair (V chunk is fully contiguous in vpack). VGPR target <=128 for
// 4 waves/SIMD -> 2 blocks/CU residency.
constexpr int PKW = 136;

__global__ __launch_bounds__(512, 4) void attn_mfma(const unsigned short* __restrict__ qpack,
                                                    const unsigned short* __restrict__ kpack,
                                                    const unsigned short* __restrict__ vpack,
                                                    unsigned short* __restrict__ ctx) {
    __shared__ __align__(16) unsigned short KV[16384];         // 16 KB K + 16 KB V
    __shared__ __align__(16) unsigned short Ps[8 * 16 * PKW];  // per-wave P [16][136]

    const int tid = threadIdx.x;
    const int lane = tid & 63;
    const int wv = tid >> 6;
    const int fm = lane & 15;
    const int quad = lane >> 4;
    const int h = blockIdx.x, b = blockIdx.y, half = blockIdx.z;
    const int q0 = half * 128 + wv * 16;

    const unsigned short* qp = qpack + (size_t)(b * H + h) * 16384;
    const unsigned short* kp = kpack + (size_t)(b * H + h) * 32768;
    const unsigned short* vp = vpack + (size_t)(b * H + h) * 32768;

    const s16x8 aq0 = *(const s16x8*)&qp[quad * 2048 + (q0 + fm) * 8];
    const s16x8 aq1 = *(const s16x8*)&qp[(4 + quad) * 2048 + (q0 + fm) * 8];

    const float scale = 0.125f;   // 1/sqrt(64)
    f32x4 co[4];
#pragma unroll
    for (int n = 0; n < 4; n++) co[n] = (f32x4){0.f, 0.f, 0.f, 0.f};
    float m_r[4], l_r[4];
#pragma unroll
    for (int r = 0; r < 4; r++) { m_r[r] = -1e30f; l_r[r] = 0.f; }
    unsigned short* Pw = Ps + wv * (16 * PKW);

    for (int c = 0; c < 4; c++) {
        __syncthreads();
        // K chunk [dgrp 8][key 128][8] (strided 2KB segments)
#pragma unroll
        for (int it = 0; it < 2; it++) {
            int f = it * 512 + tid;
            int dg = f >> 7, kk = f & 127;
            load_lds16(kp + dg * 4096 + (c * 128 + kk) * 8, KV + f * 8);
        }
        // V chunk (fully contiguous 16 KB): [kg 16][d 64][8]
#pragma unroll
        for (int it = 0; it < 2; it++) {
            int f = it * 512 + tid;
            load_lds16(vp + c * 8192 + f * 8, KV + 8192 + f * 8);
        }
        __syncthreads();

        // scores for this chunk (8 tiles of 16 keys)
        f32x4 sc[8];
#pragma unroll
        for (int t = 0; t < 8; t++) {
            s16x8 bk0 = *(const s16x8*)&KV[(quad * 128 + t * 16 + fm) * 8];
            s16x8 bk1 = *(const s16x8*)&KV[((4 + quad) * 128 + t * 16 + fm) * 8];
            f32x4 a = (f32x4){0.f, 0.f, 0.f, 0.f};
            a = __builtin_amdgcn_mfma_f32_16x16x32_bf16(aq0, bk0, a, 0, 0, 0);
            a = __builtin_amdgcn_mfma_f32_16x16x32_bf16(aq1, bk1, a, 0, 0, 0);
            sc[t] = a;
        }

        // online softmax update (rows live on this quad's 16 lanes)
        float mn[4];
#pragma unroll
        for (int r = 0; r < 4; r++) {
            float m = sc[0][r];
#pragma unroll
            for (int t = 1; t < 8; t++) m = fmaxf(m, sc[t][r]);
            mn[r] = m;
        }
#pragma unroll
        for (int o = 1; o < 16; o <<= 1)
#pragma unroll
            for (int r = 0; r < 4; r++) mn[r] = fmaxf(mn[r], __shfl_xor(mn[r], o));
        float alpha[4];
#pragma unroll
        for (int r = 0; r < 4; r++) {
            float mnew = fmaxf(m_r[r], mn[r]);
            alpha[r] = __expf((m_r[r] - mnew) * scale);
            m_r[r] = mnew;
        }
        float ls[4] = {0.f, 0.f, 0.f, 0.f};
#pragma unroll
        for (int t = 0; t < 8; t++)
#pragma unroll
            for (int r = 0; r < 4; r++) {
                float e = __expf((sc[t][r] - m_r[r]) * scale);
                sc[t][r] = e;
                ls[r] += e;
            }
#pragma unroll
        for (int o = 1; o < 16; o <<= 1)
#pragma unroll
            for (int r = 0; r < 4; r++) ls[r] += __shfl_xor(ls[r], o);
#pragma unroll
        for (int r = 0; r < 4; r++) l_r[r] = l_r[r] * alpha[r] + ls[r];
#pragma unroll
        for (int n = 0; n < 4; n++)
#pragma unroll
            for (int r = 0; r < 4; r++) co[n][r] *= alpha[r];

        // P (C-layout regs) -> wave-private LDS [q 16][key 128]
#pragma unroll
        for (int t = 0; t < 8; t++)
#pragma unroll
            for (int r = 0; r < 4; r++)
                Pw[(quad * 4 + r) * PKW + t * 16 + fm] = f2bf(sc[t][r]);
        // within-wave ds ordering via lgkmcnt; Pw is wave-private -> no barrier

        // PV for this chunk: 4 k-steps of 32 keys
#pragma unroll
        for (int s = 0; s < 4; s++) {
            s16x8 ap = *(const s16x8*)&Pw[fm * PKW + s * 32 + quad * 8];
#pragma unroll
            for (int n = 0; n < 4; n++) {
                s16x8 bv = *(const s16x8*)&KV[8192 + ((s * 4 + quad) * 64 + n * 16 + fm) * 8];
                co[n] = __builtin_amdgcn_mfma_f32_16x16x32_bf16(ap, bv, co[n], 0, 0, 0);
            }
        }
    }

    const size_t obase = (size_t)(b * LMAX + q0) * D + h * DH;
#pragma unroll
    for (int r = 0; r < 4; r++) {
        float inv = 1.f / l_r[r];
#pragma unroll
        for (int n = 0; n < 4; n++)
            ctx[obase + (size_t)(quad * 4 + r) * D + n * 16 + fm] = f2bf(co[n][r] * inv);
    }
}

// ---------------------------------------------------------------------------
// Barrier-free fused (partial-sum + bias) + LayerNorm + segment-mean.
__global__ __launch_bounds__(256) void lnmean_kernel(const unsigned short* __restrict__ f1a,
                                                     const unsigned short* __restrict__ f1b,
                                                     const float* __restrict__ bo,
                                                     const float* __restrict__ g,
                                                     const float* __restrict__ bb,
                                                     const int* __restrict__ counts,
                                                     float* __restrict__ msum) {
    int b = blockIdx.x;
    int t = threadIdx.x;
    int wv = t >> 6, lane = t & 63;
    int cnt = counts[b];
    int s0 = blockIdx.y * 32 + wv * 8;
    int s1 = min(cnt, s0 + 8);

    float4 gg[4], bv[4], bo4[4];
#pragma unroll
    for (int c = 0; c < 4; c++) {
        gg[c]  = *(const float4*)&g[c * 256 + lane * 4];
        bv[c]  = *(const float4*)&bb[c * 256 + lane * 4];
        bo4[c] = *(const float4*)&bo[c * 256 + lane * 4];
    }
    float4 acc[4];
#pragma unroll
    for (int c = 0; c < 4; c++) acc[c] = (float4){0.f, 0.f, 0.f, 0.f};

    for (int s = s0; s < s1; s++) {
        size_t rbase = ((size_t)(b * LMAX + s)) * D;
        float4 v[4];
        float sm = 0.f, ss = 0.f;
#pragma unroll
        for (int c = 0; c < 4; c++) {
            ushort4 ua = *(const ushort4*)&f1a[rbase + c * 256 + lane * 4];
            ushort4 ub = *(const ushort4*)&f1b[rbase + c * 256 + lane * 4];
            v[c].x = bf2f(ua.x) + bf2f(ub.x) + bo4[c].x;
            v[c].y = bf2f(ua.y) + bf2f(ub.y) + bo4[c].y;
            v[c].z = bf2f(ua.z) + bf2f(ub.z) + bo4[c].z;
            v[c].w = bf2f(ua.w) + bf2f(ub.w) + bo4[c].w;
            sm += v[c].x + v[c].y + v[c].z + v[c].w;
            ss += v[c].x * v[c].x + v[c].y * v[c].y + v[c].z * v[c].z + v[c].w * v[c].w;
        }
#pragma unroll
        for (int o = 32; o; o >>= 1) { sm += __shfl_xor(sm, o); ss += __shfl_xor(ss, o); }
        float mu = sm * (1.f / D);
        float var = ss * (1.f / D) - mu * mu;
        float r = rsqrtf(var + LN_EPS);
#pragma unroll
        for (int c = 0; c < 4; c++) {
            acc[c].x += (v[c].x - mu) * r * gg[c].x + bv[c].x;
            acc[c].y += (v[c].y - mu) * r * gg[c].y + bv[c].y;
            acc[c].z += (v[c].z - mu) * r * gg[c].z + bv[c].z;
            acc[c].w += (v[c].w - mu) * r * gg[c].w + bv[c].w;
        }
    }
    float inv = 1.f / (float)max(cnt, 1);
#pragma unroll
    for (int c = 0; c < 4; c++) {
        int base = b * D + c * 256 + lane * 4;
        atomicAdd(&msum[base + 0], acc[c].x * inv);
        atomicAdd(&msum[base + 1], acc[c].y * inv);
        atomicAdd(&msum[base + 2], acc[c].z * inv);
        atomicAdd(&msum[base + 3], acc[c].w * inv);
    }
}

// Mini projection: out[b][n] = msum[b] . proj_w[n] + bias[n]  (fp32).
__global__ __launch_bounds__(256) void tproj_kernel(const float* __restrict__ msum,
                                                    const float* __restrict__ W,
                                                    const float* __restrict__ bias,
                                                    float* __restrict__ out) {
    int lane = threadIdx.x & 63;
    int n = blockIdx.x * 4 + (threadIdx.x >> 6);
    float4 wr[4];
#pragma unroll
    for (int i = 0; i < 4; i++)
        wr[i] = *(const float4*)&W[(size_t)n * D + i * 256 + lane * 4];
    float bn = bias[n];
    for (int b = 0; b < B; b++) {
        float s = 0.f;
#pragma unroll
        for (int i = 0; i < 4; i++) {
            float4 m4 = *(const float4*)&msum[(size_t)b * D + i * 256 + lane * 4];
            s += m4.x * wr[i].x + m4.y * wr[i].y + m4.z * wr[i].z + m4.w * wr[i].w;
        }
#pragma unroll
        for (int o = 32; o; o >>= 1) s += __shfl_xor(s, o);
        if (lane == 0) out[(size_t)b * D + n] = s + bn;
    }
}

// ---------------------------------------------------------------------------
extern "C" void kernel_launch(void* const* d_in, const int* in_sizes, int n_in,
                              void* d_out, int out_size, void* d_ws, size_t ws_size,
                              hipStream_t stream) {
    const float* struct_token = (const float*)d_in[0];
    const float* text_token   = (const float*)d_in[1];
    const float* in_proj_w    = (const float*)d_in[2];
    const float* in_proj_b    = (const float*)d_in[3];
    const float* attn_out_w   = (const float*)d_in[4];
    const float* attn_out_b   = (const float*)d_in[5];
    const float* ln_g         = (const float*)d_in[6];
    const float* ln_b         = (const float*)d_in[7];
    const float* proj_w       = (const float*)d_in[8];
    const float* proj_b       = (const float*)d_in[9];
    const int*   sb           = (const int*)d_in[10];
    float* out = (float*)d_out;

    const size_t MQ  = (size_t)B * LMAX;     // 4096
    const size_t MKV = (size_t)B * LT;       // 8192

    char* p = (char*)d_ws;
    unsigned short* padded_b = (unsigned short*)p;  p += MQ * D * 2;
    unsigned short* text_b   = (unsigned short*)p;  p += MKV * D * 2;
    unsigned short* wqkv_b   = (unsigned short*)p;  p += (size_t)3 * D * D * 2;
    unsigned short* wattn_b  = (unsigned short*)p;  p += (size_t)D * D * 2;
    unsigned short* qpack    = (unsigned short*)p;  p += MQ * D * 2;
    unsigned short* kpack    = (unsigned short*)p;  p += MKV * D * 2;
    unsigned short* vpack    = (unsigned short*)p;  p += MKV * D * 2;
    unsigned short* ctx_b    = (unsigned short*)p;  p += MQ * D * 2;
    unsigned short* f1a      = (unsigned short*)p;  p += MQ * D * 2;
    unsigned short* f1b      = (unsigned short*)p;  p += MQ * D * 2;
    float* msum = (float*)p;  p += (size_t)B * D * 4;
    int* counts = (int*)p;  p += B * 4;
    int* starts = (int*)p;  p += B * 4;

    // casts + prep + scatter + msum-zero, one dispatch (6274 blocks)
    cast3_prep_scatter<<<6274, 256, 0, stream>>>(
        text_token, text_b, (int)(MKV * D),
        in_proj_w,  wqkv_b, 3 * D * D,
        attn_out_w, wattn_b, D * D,
        sb, counts, starts,
        struct_token, padded_b, msum);

    qkv_fused<<<1280, 256, 0, stream>>>(padded_b, text_b, wqkv_b, in_proj_b,
                                        qpack, kpack, vpack);

    attn_mfma<<<dim3(H, B, 2), 512, 0, stream>>>(qpack, kpack, vpack, ctx_b);

    gemm_bf2<<<512, 256, 0, stream>>>(ctx_b, wattn_b, f1a, f1b, D, D);

    lnmean_kernel<<<dim3(B, 8), 256, 0, stream>>>(f1a, f1b, attn_out_b, ln_g, ln_b, counts, msum);

    tproj_kernel<<<256, 256, 0, stream>>>(msum, proj_w, proj_b, out);
}